// Round 15
// baseline (470.239 us; speedup 1.0000x reference)
//
#include <hip/hip_runtime.h>
#include <hip/hip_bf16.h>
#include <math.h>

#define L_    512
#define F_    64
#define M_    (F_*L_)   // 32768
#define D2_   128
#define H_    256
#define LOG2E_ 1.4426950408889634f

typedef unsigned short u16;
typedef __attribute__((ext_vector_type(8))) short s16x8;
typedef __attribute__((ext_vector_type(4))) float f32x4;

__device__ inline u16 bf_hi(float x) {
  union { float f; unsigned u; } v; v.f = x;
  unsigned r = v.u + 0x7fffu + ((v.u >> 16) & 1u);
  return (u16)(r >> 16);
}
__device__ inline float bf_to_f(u16 h) {
  union { float f; unsigned u; } v; v.u = ((unsigned)h) << 16; return v.f;
}
__device__ inline void split2(float x, u16& h, u16& l) {
  h = bf_hi(x);
  l = bf_hi(x - bf_to_f(h));
}
__device__ inline float exp2_fast(float x) {
#if __has_builtin(__builtin_amdgcn_exp2f)
  return __builtin_amdgcn_exp2f(x);
#else
  return __expf(x * 0.6931471805599453f);
#endif
}
__device__ inline float rcp_fast(float x) {
#if __has_builtin(__builtin_amdgcn_rcpf)
  return __builtin_amdgcn_rcpf(x);
#else
  return 1.f/x;
#endif
}

// U' row-split thresholds (rows of 512 fp32). Frame-aligned: 36*512, 52*512.
#define RSPLIT_A 18432
#define RSPLIT_B 26624

// ---------------- geometry: center + covariance + 3x3 eigh ----------------
__global__ void geom_kernel(const float* __restrict__ cords, const float* __restrict__ mask,
                            float* __restrict__ misc) {
  int b = blockIdx.x;
  int t = threadIdx.x;
  __shared__ float red[4][256];
  float sx=0.f, sy=0.f, sz=0.f, sm=0.f;
  for (int l = t; l < 512; l += 256) {
    float m = mask[b*512 + l];
    const float* X = cords + ((size_t)(b*512 + l)*4 + 1)*3;
    sx += X[0]*m; sy += X[1]*m; sz += X[2]*m; sm += m;
  }
  red[0][t]=sx; red[1][t]=sy; red[2][t]=sz; red[3][t]=sm;
  __syncthreads();
  for (int off=128; off>0; off>>=1) {
    if (t < off) { red[0][t]+=red[0][t+off]; red[1][t]+=red[1][t+off];
                   red[2][t]+=red[2][t+off]; red[3][t]+=red[3][t+off]; }
    __syncthreads();
  }
  float inv = 1.f/red[3][0];
  float cx = red[0][0]*inv, cy = red[1][0]*inv, cz = red[2][0]*inv;
  __syncthreads();
  __shared__ float red6[6][256];
  float c00=0,c01=0,c02=0,c11=0,c12=0,c22=0;
  for (int l = t; l < 512; l += 256) {
    float m = mask[b*512+l];
    const float* X = cords + ((size_t)(b*512+l)*4 + 1)*3;
    float x = X[0]-cx*m, y = X[1]-cy*m, z = X[2]-cz*m;
    c00+=x*x; c01+=x*y; c02+=x*z; c11+=y*y; c12+=y*z; c22+=z*z;
  }
  red6[0][t]=c00; red6[1][t]=c01; red6[2][t]=c02;
  red6[3][t]=c11; red6[4][t]=c12; red6[5][t]=c22;
  __syncthreads();
  for (int off=128; off>0; off>>=1) {
    if (t < off) for (int j=0;j<6;j++) red6[j][t]+=red6[j][t+off];
    __syncthreads();
  }
  if (t == 0) {
    double A[3][3], V[3][3];
    A[0][0]=red6[0][0]; A[0][1]=A[1][0]=red6[1][0]; A[0][2]=A[2][0]=red6[2][0];
    A[1][1]=red6[3][0]; A[1][2]=A[2][1]=red6[4][0]; A[2][2]=red6[5][0];
    for (int j=0;j<3;j++) for (int i=0;i<3;i++) V[j][i] = (i==j)?1.0:0.0;
    for (int sweep=0; sweep<10; ++sweep) {
      for (int p=0;p<2;p++) for (int q=p+1;q<3;q++) {
        double apq = A[p][q];
        if (fabs(apq) < 1e-18) continue;
        double app = A[p][p], aqq = A[q][q];
        double tau = (aqq - app) / (2.0*apq);
        double tt = (tau >= 0.0) ? 1.0/(tau + sqrt(1.0+tau*tau))
                                 : 1.0/(tau - sqrt(1.0+tau*tau));
        double cc = 1.0/sqrt(1.0+tt*tt), ss = tt*cc;
        A[p][p] = app - tt*apq;
        A[q][q] = aqq + tt*apq;
        A[p][q] = A[q][p] = 0.0;
        int r = 3 - p - q;
        double arp = A[r][p], arq = A[r][q];
        A[r][p] = A[p][r] = cc*arp - ss*arq;
        A[r][q] = A[q][r] = ss*arp + cc*arq;
        for (int rr2=0; rr2<3; ++rr2) {
          double vrp = V[rr2][p], vrq = V[rr2][q];
          V[rr2][p] = cc*vrp - ss*vrq;
          V[rr2][q] = ss*vrp + cc*vrq;
        }
      }
    }
    double w[3] = {A[0][0], A[1][1], A[2][2]};
    int idx[3] = {0,1,2};
    for (int i=0;i<2;i++) for (int j=0;j<2-i;j++)
      if (w[idx[j]] > w[idx[j+1]]) { int tmp=idx[j]; idx[j]=idx[j+1]; idx[j+1]=tmp; }
    for (int jj=0;jj<3;jj++) for (int ii=0;ii<3;ii++)
      misc[b*12 + jj*3 + ii] = (float)V[jj][idx[ii]];
    misc[b*12+9]=cx; misc[b*12+10]=cy; misc[b*12+11]=cz;
  }
}

// ---------------- build h0 pairs: [F*L][288] = [hX(3) | emb(256) | 0-pad(29)] ----
__global__ void build_h0(const int* __restrict__ seqs, const float* __restrict__ cords,
                         const float* __restrict__ mask, const float* __restrict__ emb,
                         const float* __restrict__ misc,
                         u16* __restrict__ h0h, u16* __restrict__ h0l) {
  int t = threadIdx.x;
  int r = blockIdx.x*4 + (t >> 6);
  int lane = t & 63;
  int f = r >> 9, l = r & 511;
  int b = f >> 3, o = f & 7;
  u16* rh = h0h + (size_t)r * 288;
  u16* rl = h0l + (size_t)r * 288;
  if (lane == 0) {
    float m = mask[b*512 + l];
    const float* X = cords + ((size_t)(b*512 + l)*4 + 1)*3;
    const float* mb = misc + b*12;
    float x = X[0]-mb[9]*m, y = X[1]-mb[10]*m, z = X[2]-mb[11]*m;
    #pragma unroll
    for (int i=0;i<3;i++) {
      float sgn = ((o >> (2-i)) & 1) ? 1.f : -1.f;
      float val = sgn * (mb[0+i]*x + mb[3+i]*y + mb[6+i]*z);
      u16 h,lo; split2(val,h,lo); rh[i]=h; rl[i]=lo;
    }
  }
  if (lane < 29) { rh[259+lane] = 0; rl[259+lane] = 0; }
  int s = seqs[b*512 + l];
  if (s < 0) s = 82;
  const float4 e4 = *((const float4*)(emb + (size_t)s*256) + lane);
  float ev[4] = {e4.x, e4.y, e4.z, e4.w};
  #pragma unroll
  for (int i=0;i<4;i++) {
    u16 h,lo; split2(ev[i],h,lo);
    rh[3 + lane*4 + i] = h; rl[3 + lane*4 + i] = lo;
  }
}

// ---------------- Wqk = Wq@Wk, Wqv = Wq@Wv (fp32) ----------------
__global__ void prep_wqkv_mul(const float* __restrict__ Wq, const float* __restrict__ Wk,
                              const float* __restrict__ Wv,
                              float* __restrict__ wqk, float* __restrict__ wqv) {
  int k = blockIdx.x;
  int y = blockIdx.y;
  int t = threadIdx.x;    // 0..127
  __shared__ float row[128];
  row[t] = Wq[(size_t)k*128 + t];
  __syncthreads();
  const float* W2 = y ? Wv : Wk;
  float acc = 0.f;
  for (int j = 0; j < 128; j++) acc += row[j] * W2[(size_t)j*128 + t];
  (y ? wqv : wqk)[(size_t)k*128 + t] = acc;
}

// ---------------- wT3: [Wq|Wqk|Wqv] transpose+split, rows 0..383, stride KPq ----
__global__ void prep_wT3(const float* __restrict__ Wq, const float* __restrict__ wqk,
                         const float* __restrict__ wqv,
                         u16* __restrict__ Th, u16* __restrict__ Tl,
                         int K, int KP) {
  int y = blockIdx.y;
  int n = blockIdx.x;   // 0..127
  const float* W = (y==0) ? Wq : (y==1) ? wqk : wqv;
  int row = y*128 + n;
  for (int k = threadIdx.x; k < KP; k += 128) {
    float x = (k < K) ? W[(size_t)k*128 + n] : 0.f;
    u16 h,l; split2(x,h,l);
    Th[(size_t)row*KP + k] = h; Tl[(size_t)row*KP + k] = l;
  }
}

// wuT[(dir*512 + d*4+g)][k]; gates 1,2 scaled by -log2(e). Also nbf/nbr vectors.
__global__ void prep_wu(const float* __restrict__ Wu, u16* __restrict__ Th, u16* __restrict__ Tl,
                        const float* __restrict__ bfv, const float* __restrict__ brv,
                        float* __restrict__ nbf, float* __restrict__ nbr) {
  int n = blockIdx.x;    // 0..511
  int dir = blockIdx.y;  // 0..1
  int k = threadIdx.x;   // 0..127
  int d = n >> 2, g = n & 3;
  float x = Wu[(size_t)k*1024 + (dir*4+g)*128 + d];
  if (g == 1 || g == 2) x *= -LOG2E_;
  u16 h,l; split2(x,h,l);
  size_t o = ((size_t)dir*512 + n)*128 + k;
  Th[o]=h; Tl[o]=l;
  if (n == 0) {
    nbf[dir*128 + k] = bfv[dir*128 + k] * (-LOG2E_);
    nbr[dir*128 + k] = brv[dir*128 + k] * (-LOG2E_);
  }
}

// ---------------- split-bf16 MFMA GEMM ----------------
// EPI: 2 = qkT fp32 scale+mask (fallback); 3 = pv + residual -> pairs (fallback);
//      4 = U' fp32 with gate transform (LDS-staged operands), dual-dir triples;
//      5 = fused qkv (y:0=q pairs,1=k pairs,2=vT pairs)
template<int EPI>
__global__ __launch_bounds__(256) void gemm_bb(
    const u16* __restrict__ Ah, const u16* __restrict__ Al,
    const u16* __restrict__ Bh, const u16* __restrict__ Bl,
    int KP, int lda, int ldb,
    long aBatch, long bBatch, long cBatch,
    u16* __restrict__ Ch, u16* __restrict__ Cl, int ldc,
    u16* __restrict__ Dh, u16* __restrict__ Dl,
    u16* __restrict__ Eh, u16* __restrict__ El,
    float* __restrict__ F0, float* __restrict__ F1, float* __restrict__ F2,
    float* __restrict__ F3, float* __restrict__ F4, float* __restrict__ F5,
    const u16* __restrict__ rh, const u16* __restrict__ rl,
    const float* __restrict__ maskp, const float* __restrict__ nbf,
    const float* __restrict__ nbr, float scale, int dirOff)
{
  __shared__ u16 As[2][128][40];
  __shared__ u16 Bs[2][128][40];
  __shared__ float epsM[128];
  __shared__ float epsA[128];
  const int t = threadIdx.x;
  const int z = blockIdx.z;
  const int bm = blockIdx.x * 128, bn = blockIdx.y * 128;
  Ah += (size_t)z * aBatch; Al += (size_t)z * aBatch;
  Bh += (size_t)z * bBatch; Bl += (size_t)z * bBatch;

  const int lane = t & 63;
  const int w = t >> 6, wr = w >> 1, wc = w & 1;
  const int fr = lane & 15, g = lane >> 4;

  const bool isD1 = (bn >= 512);
  const int dirU = dirOff + (isD1 ? 1 : 0);
  if (EPI == 4) {
    if (t < 128) {
      int r = bm + t;
      epsM[t] = maskp[(r >> 12)*512 + (r & 511)];
      int nl = (bn + t) & 511;
      int dd = nl >> 2, gg2 = nl & 3;
      epsA[t] = (gg2==1) ? nbf[dirU*128 + dd] : (gg2==2) ? nbr[dirU*128 + dd] : 0.f;
    }
  }

  f32x4 acc[4][4] = {};

  for (int k0 = 0; k0 < KP; k0 += 32) {
    #pragma unroll
    for (int cc = 0; cc < 2; cc++) {
      int c = t + cc*256;
      int m = c >> 2, sub = c & 3;
      const size_t ga = (size_t)(bm + m)*lda + k0 + sub*8;
      const size_t gb = (size_t)(bn + m)*ldb + k0 + sub*8;
      *(int4*)&As[0][m][sub*8] = *(const int4*)(Ah + ga);
      *(int4*)&As[1][m][sub*8] = *(const int4*)(Al + ga);
      *(int4*)&Bs[0][m][sub*8] = *(const int4*)(Bh + gb);
      *(int4*)&Bs[1][m][sub*8] = *(const int4*)(Bl + gb);
    }
    __syncthreads();
    s16x8 af[4][2], bfr[4][2];
    #pragma unroll
    for (int i = 0; i < 4; i++) {
      af[i][0]  = *(const s16x8*)&As[0][wr*64 + i*16 + fr][g*8];
      af[i][1]  = *(const s16x8*)&As[1][wr*64 + i*16 + fr][g*8];
      bfr[i][0] = *(const s16x8*)&Bs[0][wc*64 + i*16 + fr][g*8];
      bfr[i][1] = *(const s16x8*)&Bs[1][wc*64 + i*16 + fr][g*8];
    }
    #pragma unroll
    for (int mi = 0; mi < 4; mi++)
      #pragma unroll
      for (int nj = 0; nj < 4; nj++)
        acc[mi][nj] = __builtin_amdgcn_mfma_f32_16x16x32_bf16(af[mi][0], bfr[nj][0], acc[mi][nj], 0,0,0);
    #pragma unroll
    for (int mi = 0; mi < 4; mi++)
      #pragma unroll
      for (int nj = 0; nj < 4; nj++)
        acc[mi][nj] = __builtin_amdgcn_mfma_f32_16x16x32_bf16(af[mi][0], bfr[nj][1], acc[mi][nj], 0,0,0);
    #pragma unroll
    for (int mi = 0; mi < 4; mi++)
      #pragma unroll
      for (int nj = 0; nj < 4; nj++)
        acc[mi][nj] = __builtin_amdgcn_mfma_f32_16x16x32_bf16(af[mi][1], bfr[nj][0], acc[mi][nj], 0,0,0);
    __syncthreads();
  }

  const int rbase = bm + wr*64, nbase = bn + wc*64;
  float* tA = isD1 ? F3 : F0;
  float* tB = isD1 ? F4 : F1;
  float* tC = isD1 ? F5 : F2;
  const int gg = fr & 3;
  const float ovr = (gg==1) ? -16384.f : (gg==2) ? 16384.f : 0.f;

  #pragma unroll
  for (int mi = 0; mi < 4; mi++) {
    #pragma unroll
    for (int nj = 0; nj < 4; nj++) {
      #pragma unroll
      for (int rg = 0; rg < 4; rg++) {
        int r = rbase + mi*16 + g*4 + rg;
        int n = nbase + nj*16 + fr;
        float val = acc[mi][nj][rg];
        if (EPI == 2) {
          float vv = val * scale;
          if (maskp[(z>>3)*512 + n] == 0.f) vv = -1e9f;
          F0[(size_t)z*cBatch + (size_t)r*ldc + n] = vv;
        } else if (EPI == 3) {
          size_t o = (size_t)z*cBatch + (size_t)r*ldc + n;
          float vv = val + (bf_to_f(rh[o]) + bf_to_f(rl[o]));
          u16 h,l; split2(vv,h,l);
          Ch[o]=h; Cl[o]=l;
        } else if (EPI == 4) {
          int nloc = (n & 511);
          val += epsA[n - bn];
          if (epsM[r - bm] == 0.f) val = ovr;
          float* Up;
          if (r < RSPLIT_A)      Up = tA + (size_t)r*512;
          else if (r < RSPLIT_B) Up = tB + (size_t)(r - RSPLIT_A)*512;
          else                   Up = tC + (size_t)(r - RSPLIT_B)*512;
          Up[nloc] = val;
        } else {                    // 5: fused qkv
          u16 h,l; split2(val,h,l);
          if (blockIdx.y == 0) {
            size_t o = (size_t)r*128 + n;
            Ch[o]=h; Cl[o]=l;
          } else if (blockIdx.y == 1) {
            size_t o = (size_t)r*128 + (n - 128);
            Dh[o]=h; Dl[o]=l;
          } else {
            size_t o = ((size_t)(r >> 9)*128 + (n - 256))*512 + (r & 511);
            Eh[o]=h; El[o]=l;
          }
        }
      }
    }
  }
}

// ---------------- flash attention v2: Q-in-registers, full-tile K/V staging ----
// XCD swizzle kept (round-14: FETCH 200->28MB). New: Q tile held in registers
// (loaded once, not 8x); K staged as ONE 64x128 tile -> all 48 S-MFMAs after a
// single barrier; V staged as ONE 128x64 tile union-overlaid on the K buffer
// (K reads complete before B2 < overwrite point). Barriers/K-tile: ~14 -> 5.
// setprio(1) around both MFMA clusters (2 independent blocks/CU co-resident).
__global__ __launch_bounds__(256) void attn_flash(
    const u16* __restrict__ qh, const u16* __restrict__ ql,
    const u16* __restrict__ kh, const u16* __restrict__ kl,
    const u16* __restrict__ vTh, const u16* __restrict__ vTl,
    const float* __restrict__ maskp,
    u16* __restrict__ ah, u16* __restrict__ al, float scale)
{
  __shared__ __align__(16) u16 KV[2*8704];   // union: Ks[2][64][132] (16896) / Vs[2][128][68] (17408)
  __shared__ u16 Ps[2][64][68];
  __shared__ float rmaxL[2][64];
  __shared__ float rsumL[2][64];
  __shared__ float mskt[64];
  const int t = threadIdx.x;
  const int bid = blockIdx.x;            // 0..511
  const int xcd  = bid & 7;
  const int rest = bid >> 3;
  const int tile = rest & 7;
  const int f    = (rest >> 3)*8 + xcd;  // frames grouped per XCD
  const int bq = f >> 3;
  const int bm = tile * 64;
  const size_t qrow0 = (size_t)f*512 + bm;
  const int lane = t & 63;
  const int w = t >> 6, wr = w >> 1, wc = w & 1;
  const int fr = lane & 15, g = lane >> 4;

  // Q tile in registers for the whole block (2 rows x 4 k-chunks x 2 planes)
  s16x8 qf[2][4][2];
  #pragma unroll
  for (int i = 0; i < 2; i++) {
    const size_t qr = (qrow0 + wr*32 + i*16 + fr)*128;
    #pragma unroll
    for (int k0 = 0; k0 < 4; k0++) {
      qf[i][k0][0] = *(const s16x8*)(qh + qr + k0*32 + g*8);
      qf[i][k0][1] = *(const s16x8*)(ql + qr + k0*32 + g*8);
    }
  }

  float mrun[2][4], srun[2][4];
  #pragma unroll
  for (int mi=0;mi<2;mi++)
    #pragma unroll
    for (int rg=0;rg<4;rg++) { mrun[mi][rg] = -3e38f; srun[mi][rg] = 0.f; }
  f32x4 Oacc[2][4] = {};

  for (int kt = 0; kt < 8; ++kt) {
    if (t < 64) mskt[t] = maskp[bq*512 + kt*64 + t];
    // ---- stage full K tile: Ks[2][64][132]
    #pragma unroll
    for (int p = 0; p < 2; p++) {
      const u16* src = p ? kl : kh;
      #pragma unroll
      for (int ii = 0; ii < 4; ii++) {
        int id = ii*256 + t;
        int row = id >> 4, c = (id & 15)*8;
        *(int4*)&KV[p*8448 + row*132 + c] =
          *(const int4*)(src + ((size_t)f*512 + kt*64 + row)*128 + c);
      }
    }
    __syncthreads();                              // B1: K visible
    // ---- S = q k^T : 48 MFMAs, no intermediate barriers
    f32x4 Sacc[2][2] = {};
    __builtin_amdgcn_s_setprio(1);
    #pragma unroll
    for (int k0 = 0; k0 < 4; ++k0) {
      s16x8 bf2[2][2];
      #pragma unroll
      for (int nj = 0; nj < 2; nj++) {
        bf2[nj][0] = *(const s16x8*)&KV[        (wc*32 + nj*16 + fr)*132 + k0*32 + g*8];
        bf2[nj][1] = *(const s16x8*)&KV[8448 + (wc*32 + nj*16 + fr)*132 + k0*32 + g*8];
      }
      #pragma unroll
      for (int mi = 0; mi < 2; mi++)
        #pragma unroll
        for (int nj = 0; nj < 2; nj++)
          Sacc[mi][nj] = __builtin_amdgcn_mfma_f32_16x16x32_bf16(qf[mi][k0][0], bf2[nj][0], Sacc[mi][nj], 0,0,0);
      #pragma unroll
      for (int mi = 0; mi < 2; mi++)
        #pragma unroll
        for (int nj = 0; nj < 2; nj++)
          Sacc[mi][nj] = __builtin_amdgcn_mfma_f32_16x16x32_bf16(qf[mi][k0][0], bf2[nj][1], Sacc[mi][nj], 0,0,0);
      #pragma unroll
      for (int mi = 0; mi < 2; mi++)
        #pragma unroll
        for (int nj = 0; nj < 2; nj++)
          Sacc[mi][nj] = __builtin_amdgcn_mfma_f32_16x16x32_bf16(qf[mi][k0][1], bf2[nj][0], Sacc[mi][nj], 0,0,0);
    }
    __builtin_amdgcn_s_setprio(0);
    // ---- online softmax
    float mkv[2];
    mkv[0] = mskt[wc*32 + fr];
    mkv[1] = mskt[wc*32 + 16 + fr];
    float rm[2][4];
    #pragma unroll
    for (int mi=0;mi<2;mi++)
      #pragma unroll
      for (int rg=0;rg<4;rg++) rm[mi][rg] = -3e38f;
    #pragma unroll
    for (int mi=0;mi<2;mi++)
      #pragma unroll
      for (int nj=0;nj<2;nj++)
        #pragma unroll
        for (int rg=0;rg<4;rg++) {
          float sv = Sacc[mi][nj][rg]*scale;
          sv = (mkv[nj]==0.f) ? -1e9f : sv;
          Sacc[mi][nj][rg] = sv;
          rm[mi][rg] = fmaxf(rm[mi][rg], sv);
        }
    #pragma unroll
    for (int off=1; off<16; off<<=1)
      #pragma unroll
      for (int mi=0;mi<2;mi++)
        #pragma unroll
        for (int rg=0;rg<4;rg++) rm[mi][rg] = fmaxf(rm[mi][rg], __shfl_xor(rm[mi][rg], off));
    if (fr == 0) {
      #pragma unroll
      for (int mi=0;mi<2;mi++)
        #pragma unroll
        for (int rg=0;rg<4;rg++) rmaxL[wc][wr*32 + mi*16 + g*4 + rg] = rm[mi][rg];
    }
    __syncthreads();                              // B2: rmaxL visible (all K reads done)
    float alpha[2][4], rs[2][4];
    #pragma unroll
    for (int mi=0;mi<2;mi++)
      #pragma unroll
      for (int rg=0;rg<4;rg++) {
        int rl_ = wr*32 + mi*16 + g*4 + rg;
        float tmax = fmaxf(rmaxL[0][rl_], rmaxL[1][rl_]);
        float mn = fmaxf(mrun[mi][rg], tmax);
        alpha[mi][rg] = exp2_fast((mrun[mi][rg] - mn)*LOG2E_);
        mrun[mi][rg] = mn;
        rs[mi][rg] = 0.f;
      }
    #pragma unroll
    for (int mi=0;mi<2;mi++)
      #pragma unroll
      for (int nj=0;nj<2;nj++)
        #pragma unroll
        for (int rg=0;rg<4;rg++) {
          float p = exp2_fast((Sacc[mi][nj][rg] - mrun[mi][rg])*LOG2E_);
          rs[mi][rg] += p;
          u16 h,l; split2(p,h,l);
          int rl_ = wr*32 + mi*16 + g*4 + rg;
          int cl_ = wc*32 + nj*16 + fr;
          Ps[0][rl_][cl_] = h;
          Ps[1][rl_][cl_] = l;
        }
    #pragma unroll
    for (int off=1; off<16; off<<=1)
      #pragma unroll
      for (int mi=0;mi<2;mi++)
        #pragma unroll
        for (int rg=0;rg<4;rg++) rs[mi][rg] += __shfl_xor(rs[mi][rg], off);
    if (fr == 0) {
      #pragma unroll
      for (int mi=0;mi<2;mi++)
        #pragma unroll
        for (int rg=0;rg<4;rg++) rsumL[wc][wr*32 + mi*16 + g*4 + rg] = rs[mi][rg];
    }
    #pragma unroll
    for (int mi=0;mi<2;mi++)
      #pragma unroll
      for (int nj=0;nj<4;nj++)
        #pragma unroll
        for (int rg=0;rg<4;rg++) Oacc[mi][nj][rg] *= alpha[mi][rg];
    __syncthreads();                              // B3: rsumL + Ps visible
    #pragma unroll
    for (int mi=0;mi<2;mi++)
      #pragma unroll
      for (int rg=0;rg<4;rg++) {
        int rl_ = wr*32 + mi*16 + g*4 + rg;
        srun[mi][rg] = srun[mi][rg]*alpha[mi][rg] + rsumL[0][rl_] + rsumL[1][rl_];
      }
    // ---- stage full V tile into the KV union (K reads completed before B2)
    #pragma unroll
    for (int p = 0; p < 2; p++) {
      const u16* src = p ? vTl : vTh;
      #pragma unroll
      for (int ii = 0; ii < 4; ii++) {
        int id = ii*256 + t;
        int d = id >> 3, c = (id & 7)*8;
        *(int4*)&KV[p*8704 + d*68 + c] =
          *(const int4*)(src + ((size_t)f*128 + d)*512 + kt*64 + c);
      }
    }
    __syncthreads();                              // B4: V visible
    // ---- PV: 48 MFMAs, no intermediate barriers
    __builtin_amdgcn_s_setprio(1);
    #pragma unroll
    for (int k0 = 0; k0 < 2; ++k0) {
      s16x8 pa[2][2], pb[4][2];
      #pragma unroll
      for (int i = 0; i < 2; i++) {
        pa[i][0] = *(const s16x8*)&Ps[0][wr*32 + i*16 + fr][k0*32 + g*8];
        pa[i][1] = *(const s16x8*)&Ps[1][wr*32 + i*16 + fr][k0*32 + g*8];
      }
      #pragma unroll
      for (int j = 0; j < 4; j++) {
        pb[j][0] = *(const s16x8*)&KV[        (wc*64 + j*16 + fr)*68 + k0*32 + g*8];
        pb[j][1] = *(const s16x8*)&KV[8704 + (wc*64 + j*16 + fr)*68 + k0*32 + g*8];
      }
      #pragma unroll
      for (int mi = 0; mi < 2; mi++)
        #pragma unroll
        for (int nj = 0; nj < 4; nj++)
          Oacc[mi][nj] = __builtin_amdgcn_mfma_f32_16x16x32_bf16(pa[mi][0], pb[nj][0], Oacc[mi][nj], 0,0,0);
      #pragma unroll
      for (int mi = 0; mi < 2; mi++)
        #pragma unroll
        for (int nj = 0; nj < 4; nj++)
          Oacc[mi][nj] = __builtin_amdgcn_mfma_f32_16x16x32_bf16(pa[mi][0], pb[nj][1], Oacc[mi][nj], 0,0,0);
      #pragma unroll
      for (int mi = 0; mi < 2; mi++)
        #pragma unroll
        for (int nj = 0; nj < 4; nj++)
          Oacc[mi][nj] = __builtin_amdgcn_mfma_f32_16x16x32_bf16(pa[mi][1], pb[nj][0], Oacc[mi][nj], 0,0,0);
    }
    __builtin_amdgcn_s_setprio(0);
    __syncthreads();                              // B5: PV reads done before next staging
  }
  // ---- epilogue: a = O/s + q
  float inv[2][4];
  #pragma unroll
  for (int mi=0;mi<2;mi++)
    #pragma unroll
    for (int rg=0;rg<4;rg++) inv[mi][rg] = 1.f / srun[mi][rg];
  #pragma unroll
  for (int mi=0;mi<2;mi++)
    #pragma unroll
    for (int nj=0;nj<4;nj++)
      #pragma unroll
      for (int rg=0;rg<4;rg++) {
        int rl_ = wr*32 + mi*16 + g*4 + rg;
        int cl_ = wc*64 + nj*16 + fr;
        size_t o = (qrow0 + rl_)*128 + cl_;
        float val = Oacc[mi][nj][rg]*inv[mi][rg] + bf_to_f(qh[o]) + bf_to_f(ql[o]);
        u16 h,l; split2(val,h,l);
        ah[o]=h; al[o]=l;
      }
}

// ---------------- row softmax over 512 (fallback path only) ----------------
__global__ void softmax_split(float* __restrict__ S) {
  size_t row = blockIdx.x;
  float* p = S + row*512;
  u16* ph = (u16*)p;
  u16* pl = ph + 512;
  int t = threadIdx.x; // 64
  float v[8];
  float mx = -1e30f;
  #pragma unroll
  for (int i=0;i<8;i++) { v[i] = p[t + i*64]; mx = fmaxf(mx, v[i]); }
  #pragma unroll
  for (int off=32; off>0; off>>=1) mx = fmaxf(mx, __shfl_xor(mx, off));
  float sum = 0.f;
  #pragma unroll
  for (int i=0;i<8;i++) { v[i] = __expf(v[i]-mx); sum += v[i]; }
  #pragma unroll
  for (int off=32; off>0; off>>=1) sum += __shfl_xor(sum, off);
  float invs = 1.f/sum;
  #pragma unroll
  for (int i=0;i<8;i++) {
    float x = v[i]*invs;
    u16 h,l; split2(x,h,l);
    ph[t + i*64] = h; pl[t + i*64] = l;
  }
}

// ---------------- SRU scan: dir-merged, lean body, round-9 pipeline ----------
#define CH_ 8
#define LOADC(buf, ch) do { \
  int _c = (ch); \
  _Pragma("unroll") \
  for (int s = 0; s < CH_; s++) { \
    int l = (_c*CH_ + s) ^ lxor; \
    buf[s] = *(const float4*)(Ubase + (size_t)l*512); \
  } \
  __builtin_amdgcn_sched_barrier(0); \
} while(0)

#define COMPC(buf, ch) do { \
  int _c = (ch); \
  _Pragma("unroll") \
  for (int s = 0; s < CH_; s++) { \
    int l = (_c*CH_ + s) ^ lxor; \
    float4 u = buf[s]; \
    float ef = exp2_fast(fmaf(nvfd, cstate, u.y)); \
    float fg = rcp_fast(1.f + ef); \
    float er = exp2_fast(fmaf(nvrd, cstate, u.z)); \
    float rg = rcp_fast(1.f + er); \
    float cn = fmaf(fg, cstate - u.x, u.x); \
    float h  = fmaf(rg, cn - u.w, u.w); \
    cstate = cn; \
    if (PAIRS) { \
      u16 sh_, sl_; split2(h, sh_, sl_); \
      hpph[(size_t)l*256] = sh_; \
      hppl[(size_t)l*256] = sl_; \
    } else { \
      h32p[(size_t)l*256] = h; \
    } \
  } \
  __builtin_amdgcn_sched_barrier(0); \
} while(0)

template<int PAIRS>
__global__ __launch_bounds__(64, 1) void sru_scan(
                          const float* __restrict__ ua0, const float* __restrict__ ub0,
                          const float* __restrict__ uc0,
                          const float* __restrict__ ua1, const float* __restrict__ ub1,
                          const float* __restrict__ uc1,
                          const float* __restrict__ vf, const float* __restrict__ vr,
                          u16* __restrict__ hph, u16* __restrict__ hpl,
                          float* __restrict__ h32, int dirArg) {
  const int blk = blockIdx.x;   // 0..127
  const int f = blk >> 1;       // frame
  const int hh = blk & 1;       // channel half
  const int dir = dirArg + blockIdx.y;
  const int t = threadIdx.x;    // 0..63
  const int lxor = dir ? 511 : 0;
  const int d = hh*64 + t;
  const float nvfd = vf[dir*128 + d] * (-LOG2E_);
  const float nvrd = vr[dir*128 + d] * (-LOG2E_);
  const size_t fbase = (size_t)f * 512;
  const float* ua = dir ? ua1 : ua0;
  const float* ub = dir ? ub1 : ub0;
  const float* uc = dir ? uc1 : uc0;
  const float* Uf;
  if (f < 36)      Uf = ua + (size_t)f*(512*512);
  else if (f < 52) Uf = ub + (size_t)(f-36)*(512*512);
  else             Uf = uc + (size_t)(f-52)*(512*512);
  const float* Ubase = Uf + d*4;
  u16* hpph = hph + fbase*256 + (size_t)dir*128 + d;
  u16* hppl = hpl + fbase*256 + (size_t)dir*128 + d;
  float* h32p = h32 + fbase*256 + (size_t)dir*128 + d;

  float4 b0[CH_], b1[CH_], b2[CH_], b3[CH_];
  LOADC(b0, 0); LOADC(b1, 1);
  float cstate = 0.f;
  #pragma unroll 1
  for (int q4 = 0; q4 < 15; q4++) {
    const int base = q4*4;
    LOADC(b2, base+2);
    COMPC(b0, base);
    LOADC(b3, base+3);
    COMPC(b1, base+1);
    LOADC(b0, base+4);
    COMPC(b2, base+2);
    LOADC(b1, base+5);
    COMPC(b3, base+3);
  }
  LOADC(b2, 62);
  COMPC(b0, 60);
  LOADC(b3, 63);
  COMPC(b1, 61);
  COMPC(b2, 62);
  COMPC(b3, 63);
}

// ---------------- mean over 8 sign-frames (reads fp32 h) ----------------
__global__ void mean_kernel(const float* __restrict__ h2, float* __restrict__ out) {
  int i = blockIdx.x*256 + threadIdx.x;   // float4 units
  int row = i >> 6;        // b*512 + l
  int c4  = i & 63;
  int b = row >> 9, l = row & 511;
  float ax=0.f, ay=0.f, az=0.f, aw=0.f;
  #pragma unroll
  for (int o=0;o<8;o++) {
    const float4* p = (const float4*)(h2 + ((size_t)((b*8+o)*512 + l))*256) + c4;
    float4 e = *p;
    ax += e.x; ay += e.y; az += e.z; aw += e.w;
  }
  float4 r; r.x = ax*0.125f; r.y = ay*0.125f; r.z = az*0.125f; r.w = aw*0.125f;
  ((float4*)out)[i] = r;
}

extern "C" void kernel_launch(void* const* d_in, const int* in_sizes, int n_in,
                              void* d_out, int out_size, void* d_ws, size_t ws_size,
                              hipStream_t stream) {
  const int*   seqs  = (const int*)d_in[0];
  const float* cords = (const float*)d_in[1];
  const float* mask  = (const float*)d_in[2];
  const float* emb   = (const float*)d_in[3];
  const float* Wq[2] = {(const float*)d_in[4],  (const float*)d_in[12]};
  const float* Wk[2] = {(const float*)d_in[5],  (const float*)d_in[13]};
  const float* Wv[2] = {(const float*)d_in[6],  (const float*)d_in[14]};
  const float* Wu[2] = {(const float*)d_in[7],  (const float*)d_in[15]};
  const float* vf[2] = {(const float*)d_in[8],  (const float*)d_in[16]};
  const float* vr[2] = {(const float*)d_in[9],  (const float*)d_in[17]};
  const float* bfp[2]= {(const float*)d_in[10], (const float*)d_in[18]};
  const float* brp[2]= {(const float*)d_in[11], (const float*)d_in[19]};

  const size_t H0_B = 2*(size_t)M_*288*2;   // 37,748,736
  const size_t Q_B  = 2*(size_t)M_*128*2;   // 16,777,216
  const size_t S_B  = (size_t)M_*512*4;     // 67,108,864
  const size_t HP_B = 2*(size_t)M_*256*2;   // 33,554,432
  const size_t W_B  = (size_t)(2*1024*128)*2 + 2*256*4;  // wuT pairs + nbf/nbr

  const size_t NEED_MERGED = 4096 + H0_B + 3*Q_B + S_B + HP_B + W_B;
  const bool merged = (ws_size >= NEED_MERGED);

  char* base = (char*)d_ws;
  float* misc = (float*)base;
  u16* h0p_h = (u16*)(base + 4096);
  u16* h0p_l = h0p_h + (size_t)M_*288;
  u16* q_h   = (u16*)(base + 4096 + H0_B);
  u16* q_l   = q_h + (size_t)M_*128;
  u16* k_h   = (u16*)(base + 4096 + H0_B + Q_B);
  u16* k_l   = k_h + (size_t)M_*128;

  u16 *vT_h, *vT_l, *a_h, *a_l;
  float *S, *tail_w;
  u16 *hp_h, *hp_l;
  float *U1A, *U1B, *U1C;
  if (merged) {
    vT_h = (u16*)(base + 4096 + H0_B + 2*Q_B);
    vT_l = vT_h + (size_t)M_*128;
    S    = (float*)(base + 4096 + H0_B + 3*Q_B);
    hp_h = (u16*)((char*)S + S_B);
    hp_l = hp_h + (size_t)M_*256;
    tail_w = (float*)((char*)hp_h + HP_B);
    U1A = (float*)h0p_h;
    U1B = (float*)q_h;
    U1C = (float*)vT_h;
    a_h = hp_h;                    // hp region: dead between qkv (consumes h) and scan (rewrites)
    a_l = hp_h + (size_t)M_*128;
  } else {
    S    = (float*)(base + 4096 + H0_B + 2*Q_B);
    hp_h = (u16*)((char*)S + S_B);
    hp_l = hp_h + (size_t)M_*256;
    vT_h = hp_h; vT_l = hp_l;
    tail_w = (float*)((char*)hp_h + HP_B);
    U1A = S; U1B = S + (size_t)RSPLIT_A*512; U1C = S + (size_t)RSPLIT_B*512;
    a_h = k_h; a_l = k_l;          // fallback: a overlays k (dead after qkT)
  }
  float* U0A = S;
  float* U0B = S + (size_t)RSPLIT_A*512;
  float* U0C = S + (size_t)RSPLIT_B*512;
  float* h32 = (float*)hp_h;

  float* wqk32 = S;
  float* wqv32 = wqk32 + 288*128;
  u16*   wT3h  = (u16*)(wqv32 + 288*128);
  u16*   wT3l  = wT3h + 384*288;
  u16* wuT_h = (u16*)tail_w;
  u16* wuT_l = wuT_h + 1024*128;
  float* nbf = (float*)(wuT_l + 1024*128);
  float* nbr = nbf + 256;

  geom_kernel<<<8, 256, 0, stream>>>(cords, mask, misc);
  build_h0<<<M_/4, 256, 0, stream>>>(seqs, cords, mask, emb, misc, h0p_h, h0p_l);

  const float scale = 0.08838834764831845f; // 1/sqrt(128)
  for (int layer = 0; layer < 2; ++layer) {
    const u16* Ah_in = layer ? hp_h : h0p_h;
    const u16* Al_in = layer ? hp_l : h0p_l;
    const int  Kq    = layer ? 256 : 259;
    const int  KPq   = layer ? 256 : 288;

    prep_wqkv_mul<<<dim3(Kq,2), 128, 0, stream>>>(Wq[layer], Wk[layer], Wv[layer], wqk32, wqv32);
    prep_wT3<<<dim3(128,3), 128, 0, stream>>>(Wq[layer], wqk32, wqv32, wT3h, wT3l, Kq, KPq);
    prep_wu<<<dim3(512,2), 128, 0, stream>>>(Wu[layer], wuT_h, wuT_l, bfp[layer], brp[layer], nbf, nbr);

    // fused [q|k|v] = h @ [Wq|Wqk|Wqv]
    gemm_bb<5><<<dim3(256,3,1), 256, 0, stream>>>(Ah_in, Al_in, wT3h, wT3l,
        KPq, KPq, KPq, 0,0,0, q_h, q_l, 128, k_h, k_l, vT_h, vT_l,
        nullptr,nullptr,nullptr,nullptr,nullptr,nullptr,
        nullptr,nullptr, nullptr,nullptr,nullptr, 0.f, 0);

    if (merged) {
      // flash attention v2, XCD-swizzled 1-D grid
      attn_flash<<<512, 256, 0, stream>>>(q_h, q_l, k_h, k_l, vT_h, vT_l,
          mask, a_h, a_l, scale);
    } else {
      gemm_bb<2><<<dim3(4,4,64), 256, 0, stream>>>(q_h, q_l, k_h, k_l,
          128, 128, 128, 512*128, 512*128, 512*512, nullptr,nullptr, 512,
          nullptr,nullptr,nullptr,nullptr,
          S,nullptr,nullptr,nullptr,nullptr,nullptr,
          nullptr,nullptr, mask,nullptr,nullptr, scale, 0);
      softmax_split<<<M_, 64, 0, stream>>>(S);
      gemm_bb<3><<<dim3(4,1,64), 256, 0, stream>>>((const u16*)S, (const u16*)S + 512, vT_h, vT_l,
          512, 1024, 512, 512*1024, 128*512, 512*128, a_h, a_l, 128,
          nullptr,nullptr,nullptr,nullptr,
          nullptr,nullptr,nullptr,nullptr,nullptr,nullptr,
          q_h, q_l, nullptr,nullptr,nullptr, 0.f, 0);
    }

    if (merged) {
      gemm_bb<4><<<dim3(256,8,1), 256, 0, stream>>>(a_h, a_l, wuT_h, wuT_l,
          128, 128, 128, 0,0,0, nullptr,nullptr, 512,
          nullptr,nullptr,nullptr,nullptr,
          U0A,U0B,U0C, U1A,U1B,U1C,
          nullptr,nullptr, mask, nbf, nbr, 0.f, 0);
      if (layer == 0)
        sru_scan<1><<<dim3(128,2), 64, 0, stream>>>(U0A,U0B,U0C, U1A,U1B,U1C,
            vf[layer], vr[layer], hp_h, hp_l, h32, 0);
      else
        sru_scan<0><<<dim3(128,2), 64, 0, stream>>>(U0A,U0B,U0C, U1A,U1B,U1C,
            vf[layer], vr[layer], hp_h, hp_l, h32, 0);
    } else {
      for (int dir = 0; dir < 2; ++dir) {
        gemm_bb<4><<<dim3(256,4,1), 256, 0, stream>>>(a_h, a_l,
            wuT_h + (size_t)dir*512*128, wuT_l + (size_t)dir*512*128,
            128, 128, 128, 0,0,0, nullptr,nullptr, 512,
            nullptr,nullptr,nullptr,nullptr,
            U0A,U0B,U0C, U0A,U0B,U0C,
            nullptr,nullptr, mask, nbf, nbr, 0.f, dir);
        if (layer == 0)
          sru_scan<1><<<dim3(128,1), 64, 0, stream>>>(U0A,U0B,U0C, U0A,U0B,U0C,
              vf[layer], vr[layer], hp_h, hp_l, h32, dir);
        else
          sru_scan<0><<<dim3(128,1), 64, 0, stream>>>(U0A,U0B,U0C, U0A,U0B,U0C,
              vf[layer], vr[layer], hp_h, hp_l, h32, dir);
      }
    }
  }
  mean_kernel<<<1024, 256, 0, stream>>>(h32, (float*)d_out);
}

// Round 16
// 441.514 us; speedup vs baseline: 1.0651x; 1.0651x over previous
//
#include <hip/hip_runtime.h>
#include <hip/hip_bf16.h>
#include <math.h>

#define L_    512
#define F_    64
#define M_    (F_*L_)   // 32768
#define D2_   128
#define H_    256
#define LOG2E_ 1.4426950408889634f

typedef unsigned short u16;
typedef __attribute__((ext_vector_type(8))) short s16x8;
typedef __attribute__((ext_vector_type(4))) float f32x4;

__device__ inline u16 bf_hi(float x) {
  union { float f; unsigned u; } v; v.f = x;
  unsigned r = v.u + 0x7fffu + ((v.u >> 16) & 1u);
  return (u16)(r >> 16);
}
__device__ inline float bf_to_f(u16 h) {
  union { float f; unsigned u; } v; v.u = ((unsigned)h) << 16; return v.f;
}
__device__ inline void split2(float x, u16& h, u16& l) {
  h = bf_hi(x);
  l = bf_hi(x - bf_to_f(h));
}
__device__ inline float exp2_fast(float x) {
#if __has_builtin(__builtin_amdgcn_exp2f)
  return __builtin_amdgcn_exp2f(x);
#else
  return __expf(x * 0.6931471805599453f);
#endif
}
__device__ inline float rcp_fast(float x) {
#if __has_builtin(__builtin_amdgcn_rcpf)
  return __builtin_amdgcn_rcpf(x);
#else
  return 1.f/x;
#endif
}

// U' row-split thresholds (rows of 512 fp32). Frame-aligned: 36*512, 52*512.
#define RSPLIT_A 18432
#define RSPLIT_B 26624

// ---------------- geometry: center + covariance + 3x3 eigh ----------------
__global__ void geom_kernel(const float* __restrict__ cords, const float* __restrict__ mask,
                            float* __restrict__ misc) {
  int b = blockIdx.x;
  int t = threadIdx.x;
  __shared__ float red[4][256];
  float sx=0.f, sy=0.f, sz=0.f, sm=0.f;
  for (int l = t; l < 512; l += 256) {
    float m = mask[b*512 + l];
    const float* X = cords + ((size_t)(b*512 + l)*4 + 1)*3;
    sx += X[0]*m; sy += X[1]*m; sz += X[2]*m; sm += m;
  }
  red[0][t]=sx; red[1][t]=sy; red[2][t]=sz; red[3][t]=sm;
  __syncthreads();
  for (int off=128; off>0; off>>=1) {
    if (t < off) { red[0][t]+=red[0][t+off]; red[1][t]+=red[1][t+off];
                   red[2][t]+=red[2][t+off]; red[3][t]+=red[3][t+off]; }
    __syncthreads();
  }
  float inv = 1.f/red[3][0];
  float cx = red[0][0]*inv, cy = red[1][0]*inv, cz = red[2][0]*inv;
  __syncthreads();
  __shared__ float red6[6][256];
  float c00=0,c01=0,c02=0,c11=0,c12=0,c22=0;
  for (int l = t; l < 512; l += 256) {
    float m = mask[b*512+l];
    const float* X = cords + ((size_t)(b*512+l)*4 + 1)*3;
    float x = X[0]-cx*m, y = X[1]-cy*m, z = X[2]-cz*m;
    c00+=x*x; c01+=x*y; c02+=x*z; c11+=y*y; c12+=y*z; c22+=z*z;
  }
  red6[0][t]=c00; red6[1][t]=c01; red6[2][t]=c02;
  red6[3][t]=c11; red6[4][t]=c12; red6[5][t]=c22;
  __syncthreads();
  for (int off=128; off>0; off>>=1) {
    if (t < off) for (int j=0;j<6;j++) red6[j][t]+=red6[j][t+off];
    __syncthreads();
  }
  if (t == 0) {
    double A[3][3], V[3][3];
    A[0][0]=red6[0][0]; A[0][1]=A[1][0]=red6[1][0]; A[0][2]=A[2][0]=red6[2][0];
    A[1][1]=red6[3][0]; A[1][2]=A[2][1]=red6[4][0]; A[2][2]=red6[5][0];
    for (int j=0;j<3;j++) for (int i=0;i<3;i++) V[j][i] = (i==j)?1.0:0.0;
    for (int sweep=0; sweep<10; ++sweep) {
      for (int p=0;p<2;p++) for (int q=p+1;q<3;q++) {
        double apq = A[p][q];
        if (fabs(apq) < 1e-18) continue;
        double app = A[p][p], aqq = A[q][q];
        double tau = (aqq - app) / (2.0*apq);
        double tt = (tau >= 0.0) ? 1.0/(tau + sqrt(1.0+tau*tau))
                                 : 1.0/(tau - sqrt(1.0+tau*tau));
        double cc = 1.0/sqrt(1.0+tt*tt), ss = tt*cc;
        A[p][p] = app - tt*apq;
        A[q][q] = aqq + tt*apq;
        A[p][q] = A[q][p] = 0.0;
        int r = 3 - p - q;
        double arp = A[r][p], arq = A[r][q];
        A[r][p] = A[p][r] = cc*arp - ss*arq;
        A[r][q] = A[q][r] = ss*arp + cc*arq;
        for (int rr2=0; rr2<3; ++rr2) {
          double vrp = V[rr2][p], vrq = V[rr2][q];
          V[rr2][p] = cc*vrp - ss*vrq;
          V[rr2][q] = ss*vrp + cc*vrq;
        }
      }
    }
    double w[3] = {A[0][0], A[1][1], A[2][2]};
    int idx[3] = {0,1,2};
    for (int i=0;i<2;i++) for (int j=0;j<2-i;j++)
      if (w[idx[j]] > w[idx[j+1]]) { int tmp=idx[j]; idx[j]=idx[j+1]; idx[j+1]=tmp; }
    for (int jj=0;jj<3;jj++) for (int ii=0;ii<3;ii++)
      misc[b*12 + jj*3 + ii] = (float)V[jj][idx[ii]];
    misc[b*12+9]=cx; misc[b*12+10]=cy; misc[b*12+11]=cz;
  }
}

// ---------------- build h0 pairs: [F*L][288] = [hX(3) | emb(256) | 0-pad(29)] ----
__global__ void build_h0(const int* __restrict__ seqs, const float* __restrict__ cords,
                         const float* __restrict__ mask, const float* __restrict__ emb,
                         const float* __restrict__ misc,
                         u16* __restrict__ h0h, u16* __restrict__ h0l) {
  int t = threadIdx.x;
  int r = blockIdx.x*4 + (t >> 6);
  int lane = t & 63;
  int f = r >> 9, l = r & 511;
  int b = f >> 3, o = f & 7;
  u16* rh = h0h + (size_t)r * 288;
  u16* rl = h0l + (size_t)r * 288;
  if (lane == 0) {
    float m = mask[b*512 + l];
    const float* X = cords + ((size_t)(b*512 + l)*4 + 1)*3;
    const float* mb = misc + b*12;
    float x = X[0]-mb[9]*m, y = X[1]-mb[10]*m, z = X[2]-mb[11]*m;
    #pragma unroll
    for (int i=0;i<3;i++) {
      float sgn = ((o >> (2-i)) & 1) ? 1.f : -1.f;
      float val = sgn * (mb[0+i]*x + mb[3+i]*y + mb[6+i]*z);
      u16 h,lo; split2(val,h,lo); rh[i]=h; rl[i]=lo;
    }
  }
  if (lane < 29) { rh[259+lane] = 0; rl[259+lane] = 0; }
  int s = seqs[b*512 + l];
  if (s < 0) s = 82;
  const float4 e4 = *((const float4*)(emb + (size_t)s*256) + lane);
  float ev[4] = {e4.x, e4.y, e4.z, e4.w};
  #pragma unroll
  for (int i=0;i<4;i++) {
    u16 h,lo; split2(ev[i],h,lo);
    rh[3 + lane*4 + i] = h; rl[3 + lane*4 + i] = lo;
  }
}

// ---------------- Wqk = Wq@Wk, Wqv = Wq@Wv (fp32) ----------------
__global__ void prep_wqkv_mul(const float* __restrict__ Wq, const float* __restrict__ Wk,
                              const float* __restrict__ Wv,
                              float* __restrict__ wqk, float* __restrict__ wqv) {
  int k = blockIdx.x;
  int y = blockIdx.y;
  int t = threadIdx.x;    // 0..127
  __shared__ float row[128];
  row[t] = Wq[(size_t)k*128 + t];
  __syncthreads();
  const float* W2 = y ? Wv : Wk;
  float acc = 0.f;
  for (int j = 0; j < 128; j++) acc += row[j] * W2[(size_t)j*128 + t];
  (y ? wqv : wqk)[(size_t)k*128 + t] = acc;
}

// ---------------- wT3: [Wq|Wqk|Wqv] transpose+split, rows 0..383, stride KPq ----
__global__ void prep_wT3(const float* __restrict__ Wq, const float* __restrict__ wqk,
                         const float* __restrict__ wqv,
                         u16* __restrict__ Th, u16* __restrict__ Tl,
                         int K, int KP) {
  int y = blockIdx.y;
  int n = blockIdx.x;   // 0..127
  const float* W = (y==0) ? Wq : (y==1) ? wqk : wqv;
  int row = y*128 + n;
  for (int k = threadIdx.x; k < KP; k += 128) {
    float x = (k < K) ? W[(size_t)k*128 + n] : 0.f;
    u16 h,l; split2(x,h,l);
    Th[(size_t)row*KP + k] = h; Tl[(size_t)row*KP + k] = l;
  }
}

// wuT[(dir*512 + d*4+g)][k]; gates 1,2 scaled by -log2(e). Also nbf/nbr vectors.
__global__ void prep_wu(const float* __restrict__ Wu, u16* __restrict__ Th, u16* __restrict__ Tl,
                        const float* __restrict__ bfv, const float* __restrict__ brv,
                        float* __restrict__ nbf, float* __restrict__ nbr) {
  int n = blockIdx.x;    // 0..511
  int dir = blockIdx.y;  // 0..1
  int k = threadIdx.x;   // 0..127
  int d = n >> 2, g = n & 3;
  float x = Wu[(size_t)k*1024 + (dir*4+g)*128 + d];
  if (g == 1 || g == 2) x *= -LOG2E_;
  u16 h,l; split2(x,h,l);
  size_t o = ((size_t)dir*512 + n)*128 + k;
  Th[o]=h; Tl[o]=l;
  if (n == 0) {
    nbf[dir*128 + k] = bfv[dir*128 + k] * (-LOG2E_);
    nbr[dir*128 + k] = brv[dir*128 + k] * (-LOG2E_);
  }
}

// ---------------- qkv GEMM, 64-row M-tiles for occupancy ----------------
// grid (512, 3): 1536 blocks (6/CU schedulable, 5/CU by LDS 30.7KB) vs the old
// 768 (3/CU, Occupancy 12%). 4 waves each own a 64x32 output stripe; same
// verified fragment mapping + 3-pass split-bf16. y: 0=q pairs, 1=k pairs, 2=vT.
__global__ __launch_bounds__(256) void gemm_qkv(
    const u16* __restrict__ Ah, const u16* __restrict__ Al,
    const u16* __restrict__ Bh, const u16* __restrict__ Bl,
    int KP,
    u16* __restrict__ Ch, u16* __restrict__ Cl,
    u16* __restrict__ Dh, u16* __restrict__ Dl,
    u16* __restrict__ Eh, u16* __restrict__ El)
{
  __shared__ u16 As[2][64][40];
  __shared__ u16 Bs[2][128][40];
  const int t = threadIdx.x;
  const int bm = blockIdx.x * 64, bn = blockIdx.y * 128;
  const int lane = t & 63;
  const int w = t >> 6;                 // wave = 32-col stripe
  const int fr = lane & 15, g = lane >> 4;

  f32x4 acc[4][2] = {};

  for (int k0 = 0; k0 < KP; k0 += 32) {
    {
      int m = t >> 2, sub = t & 3;
      const size_t ga = (size_t)(bm + m)*KP + k0 + sub*8;
      *(int4*)&As[0][m][sub*8] = *(const int4*)(Ah + ga);
      *(int4*)&As[1][m][sub*8] = *(const int4*)(Al + ga);
    }
    #pragma unroll
    for (int cc = 0; cc < 2; cc++) {
      int c = t + cc*256;
      int m = c >> 2, sub = c & 3;
      const size_t gb = (size_t)(bn + m)*KP + k0 + sub*8;
      *(int4*)&Bs[0][m][sub*8] = *(const int4*)(Bh + gb);
      *(int4*)&Bs[1][m][sub*8] = *(const int4*)(Bl + gb);
    }
    __syncthreads();
    s16x8 af[4][2], bfr[2][2];
    #pragma unroll
    for (int i = 0; i < 4; i++) {
      af[i][0] = *(const s16x8*)&As[0][i*16 + fr][g*8];
      af[i][1] = *(const s16x8*)&As[1][i*16 + fr][g*8];
    }
    #pragma unroll
    for (int j = 0; j < 2; j++) {
      bfr[j][0] = *(const s16x8*)&Bs[0][w*32 + j*16 + fr][g*8];
      bfr[j][1] = *(const s16x8*)&Bs[1][w*32 + j*16 + fr][g*8];
    }
    #pragma unroll
    for (int mi = 0; mi < 4; mi++)
      #pragma unroll
      for (int nj = 0; nj < 2; nj++)
        acc[mi][nj] = __builtin_amdgcn_mfma_f32_16x16x32_bf16(af[mi][0], bfr[nj][0], acc[mi][nj], 0,0,0);
    #pragma unroll
    for (int mi = 0; mi < 4; mi++)
      #pragma unroll
      for (int nj = 0; nj < 2; nj++)
        acc[mi][nj] = __builtin_amdgcn_mfma_f32_16x16x32_bf16(af[mi][0], bfr[nj][1], acc[mi][nj], 0,0,0);
    #pragma unroll
    for (int mi = 0; mi < 4; mi++)
      #pragma unroll
      for (int nj = 0; nj < 2; nj++)
        acc[mi][nj] = __builtin_amdgcn_mfma_f32_16x16x32_bf16(af[mi][1], bfr[nj][0], acc[mi][nj], 0,0,0);
    __syncthreads();
  }

  #pragma unroll
  for (int mi = 0; mi < 4; mi++) {
    #pragma unroll
    for (int nj = 0; nj < 2; nj++) {
      #pragma unroll
      for (int rg = 0; rg < 4; rg++) {
        int r = bm + mi*16 + g*4 + rg;
        int n = bn + w*32 + nj*16 + fr;
        float val = acc[mi][nj][rg];
        u16 h,l; split2(val,h,l);
        if (blockIdx.y == 0) {
          size_t o = (size_t)r*128 + n;
          Ch[o]=h; Cl[o]=l;
        } else if (blockIdx.y == 1) {
          size_t o = (size_t)r*128 + (n - 128);
          Dh[o]=h; Dl[o]=l;
        } else {
          size_t o = ((size_t)(r >> 9)*128 + (n - 256))*512 + (r & 511);
          Eh[o]=h; El[o]=l;
        }
      }
    }
  }
}

// ---------------- split-bf16 MFMA GEMM ----------------
// EPI: 2 = qkT fp32 scale+mask (fallback); 3 = pv + residual -> pairs (fallback);
//      4 = U' fp32 with gate transform (LDS-staged operands), dual-dir triples
template<int EPI>
__global__ __launch_bounds__(256) void gemm_bb(
    const u16* __restrict__ Ah, const u16* __restrict__ Al,
    const u16* __restrict__ Bh, const u16* __restrict__ Bl,
    int KP, int lda, int ldb,
    long aBatch, long bBatch, long cBatch,
    u16* __restrict__ Ch, u16* __restrict__ Cl, int ldc,
    float* __restrict__ F0, float* __restrict__ F1, float* __restrict__ F2,
    float* __restrict__ F3, float* __restrict__ F4, float* __restrict__ F5,
    const u16* __restrict__ rh, const u16* __restrict__ rl,
    const float* __restrict__ maskp, const float* __restrict__ nbf,
    const float* __restrict__ nbr, float scale, int dirOff)
{
  __shared__ u16 As[2][128][40];
  __shared__ u16 Bs[2][128][40];
  __shared__ float epsM[128];
  __shared__ float epsA[128];
  const int t = threadIdx.x;
  const int z = blockIdx.z;
  const int bm = blockIdx.x * 128, bn = blockIdx.y * 128;
  Ah += (size_t)z * aBatch; Al += (size_t)z * aBatch;
  Bh += (size_t)z * bBatch; Bl += (size_t)z * bBatch;

  const int lane = t & 63;
  const int w = t >> 6, wr = w >> 1, wc = w & 1;
  const int fr = lane & 15, g = lane >> 4;

  const bool isD1 = (bn >= 512);
  const int dirU = dirOff + (isD1 ? 1 : 0);
  if (EPI == 4) {
    if (t < 128) {
      int r = bm + t;
      epsM[t] = maskp[(r >> 12)*512 + (r & 511)];
      int nl = (bn + t) & 511;
      int dd = nl >> 2, gg2 = nl & 3;
      epsA[t] = (gg2==1) ? nbf[dirU*128 + dd] : (gg2==2) ? nbr[dirU*128 + dd] : 0.f;
    }
  }

  f32x4 acc[4][4] = {};

  for (int k0 = 0; k0 < KP; k0 += 32) {
    #pragma unroll
    for (int cc = 0; cc < 2; cc++) {
      int c = t + cc*256;
      int m = c >> 2, sub = c & 3;
      const size_t ga = (size_t)(bm + m)*lda + k0 + sub*8;
      const size_t gb = (size_t)(bn + m)*ldb + k0 + sub*8;
      *(int4*)&As[0][m][sub*8] = *(const int4*)(Ah + ga);
      *(int4*)&As[1][m][sub*8] = *(const int4*)(Al + ga);
      *(int4*)&Bs[0][m][sub*8] = *(const int4*)(Bh + gb);
      *(int4*)&Bs[1][m][sub*8] = *(const int4*)(Bl + gb);
    }
    __syncthreads();
    s16x8 af[4][2], bfr[4][2];
    #pragma unroll
    for (int i = 0; i < 4; i++) {
      af[i][0]  = *(const s16x8*)&As[0][wr*64 + i*16 + fr][g*8];
      af[i][1]  = *(const s16x8*)&As[1][wr*64 + i*16 + fr][g*8];
      bfr[i][0] = *(const s16x8*)&Bs[0][wc*64 + i*16 + fr][g*8];
      bfr[i][1] = *(const s16x8*)&Bs[1][wc*64 + i*16 + fr][g*8];
    }
    #pragma unroll
    for (int mi = 0; mi < 4; mi++)
      #pragma unroll
      for (int nj = 0; nj < 4; nj++)
        acc[mi][nj] = __builtin_amdgcn_mfma_f32_16x16x32_bf16(af[mi][0], bfr[nj][0], acc[mi][nj], 0,0,0);
    #pragma unroll
    for (int mi = 0; mi < 4; mi++)
      #pragma unroll
      for (int nj = 0; nj < 4; nj++)
        acc[mi][nj] = __builtin_amdgcn_mfma_f32_16x16x32_bf16(af[mi][0], bfr[nj][1], acc[mi][nj], 0,0,0);
    #pragma unroll
    for (int mi = 0; mi < 4; mi++)
      #pragma unroll
      for (int nj = 0; nj < 4; nj++)
        acc[mi][nj] = __builtin_amdgcn_mfma_f32_16x16x32_bf16(af[mi][1], bfr[nj][0], acc[mi][nj], 0,0,0);
    __syncthreads();
  }

  const int rbase = bm + wr*64, nbase = bn + wc*64;
  float* tA = isD1 ? F3 : F0;
  float* tB = isD1 ? F4 : F1;
  float* tC = isD1 ? F5 : F2;
  const int gg = fr & 3;
  const float ovr = (gg==1) ? -16384.f : (gg==2) ? 16384.f : 0.f;

  #pragma unroll
  for (int mi = 0; mi < 4; mi++) {
    #pragma unroll
    for (int nj = 0; nj < 4; nj++) {
      #pragma unroll
      for (int rg = 0; rg < 4; rg++) {
        int r = rbase + mi*16 + g*4 + rg;
        int n = nbase + nj*16 + fr;
        float val = acc[mi][nj][rg];
        if (EPI == 2) {
          float vv = val * scale;
          if (maskp[(z>>3)*512 + n] == 0.f) vv = -1e9f;
          F0[(size_t)z*cBatch + (size_t)r*ldc + n] = vv;
        } else if (EPI == 3) {
          size_t o = (size_t)z*cBatch + (size_t)r*ldc + n;
          float vv = val + (bf_to_f(rh[o]) + bf_to_f(rl[o]));
          u16 h,l; split2(vv,h,l);
          Ch[o]=h; Cl[o]=l;
        } else if (EPI == 4) {
          int nloc = (n & 511);
          val += epsA[n - bn];
          if (epsM[r - bm] == 0.f) val = ovr;
          float* Up;
          if (r < RSPLIT_A)      Up = tA + (size_t)r*512;
          else if (r < RSPLIT_B) Up = tB + (size_t)(r - RSPLIT_A)*512;
          else                   Up = tC + (size_t)(r - RSPLIT_B)*512;
          Up[nloc] = val;
        }
      }
    }
  }
}

// ---------------- flash attention (round-14 version: best measured, 70.6us) ----
// XCD swizzle: all 8 q-tiles of a frame on one XCD (FETCH 200->28MB, round 14).
__global__ __launch_bounds__(256) void attn_flash(
    const u16* __restrict__ qh, const u16* __restrict__ ql,
    const u16* __restrict__ kh, const u16* __restrict__ kl,
    const u16* __restrict__ vTh, const u16* __restrict__ vTl,
    const float* __restrict__ maskp,
    u16* __restrict__ ah, u16* __restrict__ al, float scale)
{
  __shared__ u16 As[2][64][36];
  __shared__ u16 Bs[2][128][36];
  __shared__ u16 Ps[2][64][68];
  __shared__ float rmaxL[2][64];
  __shared__ float rsumL[2][64];
  __shared__ float mskt[64];
  const int t = threadIdx.x;
  const int bid = blockIdx.x;            // 0..511
  const int xcd  = bid & 7;
  const int rest = bid >> 3;
  const int tile = rest & 7;
  const int f    = (rest >> 3)*8 + xcd;  // frames grouped per XCD
  const int bq = f >> 3;
  const int bm = tile * 64;
  const size_t qrow0 = (size_t)f*512 + bm;
  const int lane = t & 63;
  const int w = t >> 6, wr = w >> 1, wc = w & 1;
  const int fr = lane & 15, g = lane >> 4;
  const int m_ = t >> 2, sub_ = t & 3;

  float mrun[2][4], srun[2][4];
  #pragma unroll
  for (int mi=0;mi<2;mi++)
    #pragma unroll
    for (int rg=0;rg<4;rg++) { mrun[mi][rg] = -3e38f; srun[mi][rg] = 0.f; }
  f32x4 Oacc[2][4] = {};

  for (int kt = 0; kt < 8; ++kt) {
    if (t < 64) mskt[t] = maskp[bq*512 + kt*64 + t];
    f32x4 Sacc[2][2] = {};
    #pragma unroll
    for (int k0 = 0; k0 < 4; ++k0) {
      {
        const size_t ga = (qrow0 + m_)*128 + k0*32 + sub_*8;
        const size_t gb = ((size_t)f*512 + kt*64 + m_)*128 + k0*32 + sub_*8;
        *(int4*)&As[0][m_][sub_*8] = *(const int4*)(qh + ga);
        *(int4*)&As[1][m_][sub_*8] = *(const int4*)(ql + ga);
        *(int4*)&Bs[0][m_][sub_*8] = *(const int4*)(kh + gb);
        *(int4*)&Bs[1][m_][sub_*8] = *(const int4*)(kl + gb);
      }
      __syncthreads();
      s16x8 af[2][2], bf2[2][2];
      #pragma unroll
      for (int i = 0; i < 2; i++) {
        af[i][0]  = *(const s16x8*)&As[0][wr*32 + i*16 + fr][g*8];
        af[i][1]  = *(const s16x8*)&As[1][wr*32 + i*16 + fr][g*8];
        bf2[i][0] = *(const s16x8*)&Bs[0][wc*32 + i*16 + fr][g*8];
        bf2[i][1] = *(const s16x8*)&Bs[1][wc*32 + i*16 + fr][g*8];
      }
      #pragma unroll
      for (int mi = 0; mi < 2; mi++)
        #pragma unroll
        for (int nj = 0; nj < 2; nj++)
          Sacc[mi][nj] = __builtin_amdgcn_mfma_f32_16x16x32_bf16(af[mi][0], bf2[nj][0], Sacc[mi][nj], 0,0,0);
      #pragma unroll
      for (int mi = 0; mi < 2; mi++)
        #pragma unroll
        for (int nj = 0; nj < 2; nj++)
          Sacc[mi][nj] = __builtin_amdgcn_mfma_f32_16x16x32_bf16(af[mi][0], bf2[nj][1], Sacc[mi][nj], 0,0,0);
      #pragma unroll
      for (int mi = 0; mi < 2; mi++)
        #pragma unroll
        for (int nj = 0; nj < 2; nj++)
          Sacc[mi][nj] = __builtin_amdgcn_mfma_f32_16x16x32_bf16(af[mi][1], bf2[nj][0], Sacc[mi][nj], 0,0,0);
      __syncthreads();
    }
    float mkv[2];
    mkv[0] = mskt[wc*32 + fr];
    mkv[1] = mskt[wc*32 + 16 + fr];
    float rm[2][4];
    #pragma unroll
    for (int mi=0;mi<2;mi++)
      #pragma unroll
      for (int rg=0;rg<4;rg++) rm[mi][rg] = -3e38f;
    #pragma unroll
    for (int mi=0;mi<2;mi++)
      #pragma unroll
      for (int nj=0;nj<2;nj++)
        #pragma unroll
        for (int rg=0;rg<4;rg++) {
          float sv = Sacc[mi][nj][rg]*scale;
          sv = (mkv[nj]==0.f) ? -1e9f : sv;
          Sacc[mi][nj][rg] = sv;
          rm[mi][rg] = fmaxf(rm[mi][rg], sv);
        }
    #pragma unroll
    for (int off=1; off<16; off<<=1)
      #pragma unroll
      for (int mi=0;mi<2;mi++)
        #pragma unroll
        for (int rg=0;rg<4;rg++) rm[mi][rg] = fmaxf(rm[mi][rg], __shfl_xor(rm[mi][rg], off));
    if (fr == 0) {
      #pragma unroll
      for (int mi=0;mi<2;mi++)
        #pragma unroll
        for (int rg=0;rg<4;rg++) rmaxL[wc][wr*32 + mi*16 + g*4 + rg] = rm[mi][rg];
    }
    __syncthreads();
    float alpha[2][4], rs[2][4];
    #pragma unroll
    for (int mi=0;mi<2;mi++)
      #pragma unroll
      for (int rg=0;rg<4;rg++) {
        int rl_ = wr*32 + mi*16 + g*4 + rg;
        float tmax = fmaxf(rmaxL[0][rl_], rmaxL[1][rl_]);
        float mn = fmaxf(mrun[mi][rg], tmax);
        alpha[mi][rg] = exp2_fast((mrun[mi][rg] - mn)*LOG2E_);
        mrun[mi][rg] = mn;
        rs[mi][rg] = 0.f;
      }
    #pragma unroll
    for (int mi=0;mi<2;mi++)
      #pragma unroll
      for (int nj=0;nj<2;nj++)
        #pragma unroll
        for (int rg=0;rg<4;rg++) {
          float p = exp2_fast((Sacc[mi][nj][rg] - mrun[mi][rg])*LOG2E_);
          rs[mi][rg] += p;
          u16 h,l; split2(p,h,l);
          int rl_ = wr*32 + mi*16 + g*4 + rg;
          int cl_ = wc*32 + nj*16 + fr;
          Ps[0][rl_][cl_] = h;
          Ps[1][rl_][cl_] = l;
        }
    #pragma unroll
    for (int off=1; off<16; off<<=1)
      #pragma unroll
      for (int mi=0;mi<2;mi++)
        #pragma unroll
        for (int rg=0;rg<4;rg++) rs[mi][rg] += __shfl_xor(rs[mi][rg], off);
    if (fr == 0) {
      #pragma unroll
      for (int mi=0;mi<2;mi++)
        #pragma unroll
        for (int rg=0;rg<4;rg++) rsumL[wc][wr*32 + mi*16 + g*4 + rg] = rs[mi][rg];
    }
    #pragma unroll
    for (int mi=0;mi<2;mi++)
      #pragma unroll
      for (int nj=0;nj<4;nj++)
        #pragma unroll
        for (int rg=0;rg<4;rg++) Oacc[mi][nj][rg] *= alpha[mi][rg];
    __syncthreads();
    #pragma unroll
    for (int mi=0;mi<2;mi++)
      #pragma unroll
      for (int rg=0;rg<4;rg++) {
        int rl_ = wr*32 + mi*16 + g*4 + rg;
        srun[mi][rg] = srun[mi][rg]*alpha[mi][rg] + rsumL[0][rl_] + rsumL[1][rl_];
      }
    #pragma unroll
    for (int k0 = 0; k0 < 2; ++k0) {
      #pragma unroll
      for (int cc = 0; cc < 2; cc++) {
        int c = t + cc*256;
        int mv = c >> 2, sb = c & 3;
        const size_t gv = ((size_t)f*128 + mv)*512 + kt*64 + k0*32 + sb*8;
        *(int4*)&Bs[0][mv][sb*8] = *(const int4*)(vTh + gv);
        *(int4*)&Bs[1][mv][sb*8] = *(const int4*)(vTl + gv);
      }
      __syncthreads();
      s16x8 pa[2][2], pb[4][2];
      #pragma unroll
      for (int i = 0; i < 2; i++) {
        pa[i][0] = *(const s16x8*)&Ps[0][wr*32 + i*16 + fr][k0*32 + g*8];
        pa[i][1] = *(const s16x8*)&Ps[1][wr*32 + i*16 + fr][k0*32 + g*8];
      }
      #pragma unroll
      for (int j = 0; j < 4; j++) {
        pb[j][0] = *(const s16x8*)&Bs[0][wc*64 + j*16 + fr][g*8];
        pb[j][1] = *(const s16x8*)&Bs[1][wc*64 + j*16 + fr][g*8];
      }
      #pragma unroll
      for (int mi = 0; mi < 2; mi++)
        #pragma unroll
        for (int nj = 0; nj < 4; nj++)
          Oacc[mi][nj] = __builtin_amdgcn_mfma_f32_16x16x32_bf16(pa[mi][0], pb[nj][0], Oacc[mi][nj], 0,0,0);
      #pragma unroll
      for (int mi = 0; mi < 2; mi++)
        #pragma unroll
        for (int nj = 0; nj < 4; nj++)
          Oacc[mi][nj] = __builtin_amdgcn_mfma_f32_16x16x32_bf16(pa[mi][0], pb[nj][1], Oacc[mi][nj], 0,0,0);
      #pragma unroll
      for (int mi = 0; mi < 2; mi++)
        #pragma unroll
        for (int nj = 0; nj < 4; nj++)
          Oacc[mi][nj] = __builtin_amdgcn_mfma_f32_16x16x32_bf16(pa[mi][1], pb[nj][0], Oacc[mi][nj], 0,0,0);
      __syncthreads();
    }
  }
  float inv[2][4];
  #pragma unroll
  for (int mi=0;mi<2;mi++)
    #pragma unroll
    for (int rg=0;rg<4;rg++) inv[mi][rg] = 1.f / srun[mi][rg];
  #pragma unroll
  for (int mi=0;mi<2;mi++)
    #pragma unroll
    for (int nj=0;nj<4;nj++)
      #pragma unroll
      for (int rg=0;rg<4;rg++) {
        int rl_ = wr*32 + mi*16 + g*4 + rg;
        int cl_ = wc*64 + nj*16 + fr;
        size_t o = (qrow0 + rl_)*128 + cl_;
        float val = Oacc[mi][nj][rg]*inv[mi][rg] + bf_to_f(qh[o]) + bf_to_f(ql[o]);
        u16 h,l; split2(val,h,l);
        ah[o]=h; al[o]=l;
      }
}

// ---------------- row softmax over 512 (fallback path only) ----------------
__global__ void softmax_split(float* __restrict__ S) {
  size_t row = blockIdx.x;
  float* p = S + row*512;
  u16* ph = (u16*)p;
  u16* pl = ph + 512;
  int t = threadIdx.x; // 64
  float v[8];
  float mx = -1e30f;
  #pragma unroll
  for (int i=0;i<8;i++) { v[i] = p[t + i*64]; mx = fmaxf(mx, v[i]); }
  #pragma unroll
  for (int off=32; off>0; off>>=1) mx = fmaxf(mx, __shfl_xor(mx, off));
  float sum = 0.f;
  #pragma unroll
  for (int i=0;i<8;i++) { v[i] = __expf(v[i]-mx); sum += v[i]; }
  #pragma unroll
  for (int off=32; off>0; off>>=1) sum += __shfl_xor(sum, off);
  float invs = 1.f/sum;
  #pragma unroll
  for (int i=0;i<8;i++) {
    float x = v[i]*invs;
    u16 h,l; split2(x,h,l);
    ph[t + i*64] = h; pl[t + i*64] = l;
  }
}

// ---------------- SRU scan: dir-merged, lean body, round-9 pipeline ----------
#define CH_ 8
#define LOADC(buf, ch) do { \
  int _c = (ch); \
  _Pragma("unroll") \
  for (int s = 0; s < CH_; s++) { \
    int l = (_c*CH_ + s) ^ lxor; \
    buf[s] = *(const float4*)(Ubase + (size_t)l*512); \
  } \
  __builtin_amdgcn_sched_barrier(0); \
} while(0)

#define COMPC(buf, ch) do { \
  int _c = (ch); \
  _Pragma("unroll") \
  for (int s = 0; s < CH_; s++) { \
    int l = (_c*CH_ + s) ^ lxor; \
    float4 u = buf[s]; \
    float ef = exp2_fast(fmaf(nvfd, cstate, u.y)); \
    float fg = rcp_fast(1.f + ef); \
    float er = exp2_fast(fmaf(nvrd, cstate, u.z)); \
    float rg = rcp_fast(1.f + er); \
    float cn = fmaf(fg, cstate - u.x, u.x); \
    float h  = fmaf(rg, cn - u.w, u.w); \
    cstate = cn; \
    if (PAIRS) { \
      u16 sh_, sl_; split2(h, sh_, sl_); \
      hpph[(size_t)l*256] = sh_; \
      hppl[(size_t)l*256] = sl_; \
    } else { \
      h32p[(size_t)l*256] = h; \
    } \
  } \
  __builtin_amdgcn_sched_barrier(0); \
} while(0)

template<int PAIRS>
__global__ __launch_bounds__(64, 1) void sru_scan(
                          const float* __restrict__ ua0, const float* __restrict__ ub0,
                          const float* __restrict__ uc0,
                          const float* __restrict__ ua1, const float* __restrict__ ub1,
                          const float* __restrict__ uc1,
                          const float* __restrict__ vf, const float* __restrict__ vr,
                          u16* __restrict__ hph, u16* __restrict__ hpl,
                          float* __restrict__ h32, int dirArg) {
  const int blk = blockIdx.x;   // 0..127
  const int f = blk >> 1;       // frame
  const int hh = blk & 1;       // channel half
  const int dir = dirArg + blockIdx.y;
  const int t = threadIdx.x;    // 0..63
  const int lxor = dir ? 511 : 0;
  const int d = hh*64 + t;
  const float nvfd = vf[dir*128 + d] * (-LOG2E_);
  const float nvrd = vr[dir*128 + d] * (-LOG2E_);
  const size_t fbase = (size_t)f * 512;
  const float* ua = dir ? ua1 : ua0;
  const float* ub = dir ? ub1 : ub0;
  const float* uc = dir ? uc1 : uc0;
  const float* Uf;
  if (f < 36)      Uf = ua + (size_t)f*(512*512);
  else if (f < 52) Uf = ub + (size_t)(f-36)*(512*512);
  else             Uf = uc + (size_t)(f-52)*(512*512);
  const float* Ubase = Uf + d*4;
  u16* hpph = hph + fbase*256 + (size_t)dir*128 + d;
  u16* hppl = hpl + fbase*256 + (size_t)dir*128 + d;
  float* h32p = h32 + fbase*256 + (size_t)dir*128 + d;

  float4 b0[CH_], b1[CH_], b2[CH_], b3[CH_];
  LOADC(b0, 0); LOADC(b1, 1);
  float cstate = 0.f;
  #pragma unroll 1
  for (int q4 = 0; q4 < 15; q4++) {
    const int base = q4*4;
    LOADC(b2, base+2);
    COMPC(b0, base);
    LOADC(b3, base+3);
    COMPC(b1, base+1);
    LOADC(b0, base+4);
    COMPC(b2, base+2);
    LOADC(b1, base+5);
    COMPC(b3, base+3);
  }
  LOADC(b2, 62);
  COMPC(b0, 60);
  LOADC(b3, 63);
  COMPC(b1, 61);
  COMPC(b2, 62);
  COMPC(b3, 63);
}

// ---------------- mean over 8 sign-frames (reads fp32 h) ----------------
__global__ void mean_kernel(const float* __restrict__ h2, float* __restrict__ out) {
  int i = blockIdx.x*256 + threadIdx.x;   // float4 units
  int row = i >> 6;        // b*512 + l
  int c4  = i & 63;
  int b = row >> 9, l = row & 511;
  float ax=0.f, ay=0.f, az=0.f, aw=0.f;
  #pragma unroll
  for (int o=0;o<8;o++) {
    const float4* p = (const float4*)(h2 + ((size_t)((b*8+o)*512 + l))*256) + c4;
    float4 e = *p;
    ax += e.x; ay += e.y; az += e.z; aw += e.w;
  }
  float4 r; r.x = ax*0.125f; r.y = ay*0.125f; r.z = az*0.125f; r.w = aw*0.125f;
  ((float4*)out)[i] = r;
}

extern "C" void kernel_launch(void* const* d_in, const int* in_sizes, int n_in,
                              void* d_out, int out_size, void* d_ws, size_t ws_size,
                              hipStream_t stream) {
  const int*   seqs  = (const int*)d_in[0];
  const float* cords = (const float*)d_in[1];
  const float* mask  = (const float*)d_in[2];
  const float* emb   = (const float*)d_in[3];
  const float* Wq[2] = {(const float*)d_in[4],  (const float*)d_in[12]};
  const float* Wk[2] = {(const float*)d_in[5],  (const float*)d_in[13]};
  const float* Wv[2] = {(const float*)d_in[6],  (const float*)d_in[14]};
  const float* Wu[2] = {(const float*)d_in[7],  (const float*)d_in[15]};
  const float* vf[2] = {(const float*)d_in[8],  (const float*)d_in[16]};
  const float* vr[2] = {(const float*)d_in[9],  (const float*)d_in[17]};
  const float* bfp[2]= {(const float*)d_in[10], (const float*)d_in[18]};
  const float* brp[2]= {(const float*)d_in[11], (const float*)d_in[19]};

  const size_t H0_B = 2*(size_t)M_*288*2;   // 37,748,736
  const size_t Q_B  = 2*(size_t)M_*128*2;   // 16,777,216
  const size_t S_B  = (size_t)M_*512*4;     // 67,108,864
  const size_t HP_B = 2*(size_t)M_*256*2;   // 33,554,432
  const size_t W_B  = (size_t)(2*1024*128)*2 + 2*256*4;  // wuT pairs + nbf/nbr

  const size_t NEED_MERGED = 4096 + H0_B + 3*Q_B + S_B + HP_B + W_B;
  const bool merged = (ws_size >= NEED_MERGED);

  char* base = (char*)d_ws;
  float* misc = (float*)base;
  u16* h0p_h = (u16*)(base + 4096);
  u16* h0p_l = h0p_h + (size_t)M_*288;
  u16* q_h   = (u16*)(base + 4096 + H0_B);
  u16* q_l   = q_h + (size_t)M_*128;
  u16* k_h   = (u16*)(base + 4096 + H0_B + Q_B);
  u16* k_l   = k_h + (size_t)M_*128;

  u16 *vT_h, *vT_l, *a_h, *a_l;
  float *S, *tail_w;
  u16 *hp_h, *hp_l;
  float *U1A, *U1B, *U1C;
  if (merged) {
    vT_h = (u16*)(base + 4096 + H0_B + 2*Q_B);
    vT_l = vT_h + (size_t)M_*128;
    S    = (float*)(base + 4096 + H0_B + 3*Q_B);
    hp_h = (u16*)((char*)S + S_B);
    hp_l = hp_h + (size_t)M_*256;
    tail_w = (float*)((char*)hp_h + HP_B);
    U1A = (float*)h0p_h;
    U1B = (float*)q_h;
    U1C = (float*)vT_h;
    a_h = hp_h;                    // hp region: dead between qkv (consumes h) and scan (rewrites)
    a_l = hp_h + (size_t)M_*128;
  } else {
    S    = (float*)(base + 4096 + H0_B + 2*Q_B);
    hp_h = (u16*)((char*)S + S_B);
    hp_l = hp_h + (size_t)M_*256;
    vT_h = hp_h; vT_l = hp_l;
    tail_w = (float*)((char*)hp_h + HP_B);
    U1A = S; U1B = S + (size_t)RSPLIT_A*512; U1C = S + (size_t)RSPLIT_B*512;
    a_h = k_h; a_l = k_l;          // fallback: a overlays k (dead after qkT)
  }
  float* U0A = S;
  float* U0B = S + (size_t)RSPLIT_A*512;
  float* U0C = S + (size_t)RSPLIT_B*512;
  float* h32 = (float*)hp_h;

  float* wqk32 = S;
  float* wqv32 = wqk32 + 288*128;
  u16*   wT3h  = (u16*)(wqv32 + 288*128);
  u16*   wT3l  = wT3h + 384*288;
  u16* wuT_h = (u16*)tail_w;
  u16* wuT_l = wuT_h + 1024*128;
  float* nbf = (float*)(wuT_l + 1024*128);
  float* nbr = nbf + 256;

  geom_kernel<<<8, 256, 0, stream>>>(cords, mask, misc);
  build_h0<<<M_/4, 256, 0, stream>>>(seqs, cords, mask, emb, misc, h0p_h, h0p_l);

  const float scale = 0.08838834764831845f; // 1/sqrt(128)
  for (int layer = 0; layer < 2; ++layer) {
    const u16* Ah_in = layer ? hp_h : h0p_h;
    const u16* Al_in = layer ? hp_l : h0p_l;
    const int  Kq    = layer ? 256 : 259;
    const int  KPq   = layer ? 256 : 288;

    prep_wqkv_mul<<<dim3(Kq,2), 128, 0, stream>>>(Wq[layer], Wk[layer], Wv[layer], wqk32, wqv32);
    prep_wT3<<<dim3(128,3), 128, 0, stream>>>(Wq[layer], wqk32, wqv32, wT3h, wT3l, Kq, KPq);
    prep_wu<<<dim3(512,2), 128, 0, stream>>>(Wu[layer], wuT_h, wuT_l, bfp[layer], brp[layer], nbf, nbr);

    // fused [q|k|v] = h @ [Wq|Wqk|Wqv], 64-row M-tiles (1536 blocks)
    gemm_qkv<<<dim3(512,3), 256, 0, stream>>>(Ah_in, Al_in, wT3h, wT3l,
        KPq, q_h, q_l, k_h, k_l, vT_h, vT_l);

    if (merged) {
      // flash attention (round-14 version), XCD-swizzled 1-D grid
      attn_flash<<<512, 256, 0, stream>>>(q_h, q_l, k_h, k_l, vT_h, vT_l,
          mask, a_h, a_l, scale);
    } else {
      gemm_bb<2><<<dim3(4,4,64), 256, 0, stream>>>(q_h, q_l, k_h, k_l,
          128, 128, 128, 512*128, 512*128, 512*512, nullptr,nullptr, 512,
          S,nullptr,nullptr,nullptr,nullptr,nullptr,
          nullptr,nullptr, mask,nullptr,nullptr, scale, 0);
      softmax_split<<<M_, 64, 0, stream>>>(S);
      gemm_bb<3><<<dim3(4,1,64), 256, 0, stream>>>((const u16*)S, (const u16*)S + 512, vT_h, vT_l,
          512, 1024, 512, 512*1024, 128*512, 512*128, a_h, a_l, 128,
          nullptr,nullptr,nullptr,nullptr,nullptr,nullptr,
          q_h, q_l, nullptr,nullptr,nullptr, 0.f, 0);
    }

    if (merged) {
      gemm_bb<4><<<dim3(256,8,1), 256, 0, stream>>>(a_h, a_l, wuT_h, wuT_l,
          128, 128, 128, 0,0,0, nullptr,nullptr, 512,
          U0A,U0B,U0C, U1A,U1B,U1C,
          nullptr,nullptr, mask, nbf, nbr, 0.f, 0);
      if (layer == 0)
        sru_scan<1><<<dim3(128,2), 64, 0, stream>>>(U0A,U0B,U0C, U1A,U1B,U1C,
            vf[layer], vr[layer], hp_h, hp_l, h32, 0);
      else
        sru_scan<0><<<dim3(128,2), 64, 0, stream>>>(U0A,U0B,U0C, U1A,U1B,U1C,
            vf[layer], vr[layer], hp_h, hp_l, h32, 0);
    } else {
      for (int dir = 0; dir < 2; ++dir) {
        gemm_bb<4><<<dim3(256,4,1), 256, 0, stream>>>(a_h, a_l,
            wuT_h + (size_t)dir*512*128, wuT_l + (size_t)dir*512*128,
            128, 128, 128, 0,0,0, nullptr,nullptr, 512,
            U0A,U0B,U0C, U0A,U0B,U0C,
            nullptr,nullptr, mask, nbf, nbr, 0.f, dir);
        if (layer == 0)
          sru_scan<1><<<dim3(128,1), 64, 0, stream>>>(U0A,U0B,U0C, U0A,U0B,U0C,
              vf[layer], vr[layer], hp_h, hp_l, h32, dir);
        else
          sru_scan<0><<<dim3(128,1), 64, 0, stream>>>(U0A,U0B,U0C, U0A,U0B,U0C,
              vf[layer], vr[layer], hp_h, hp_l, h32, dir);
      }
    }
  }
  mean_kernel<<<1024, 256, 0, stream>>>(h32, (float*)d_out);
}